// Round 12
// baseline (69.300 us; speedup 1.0000x reference)
//
#include <hip/hip_runtime.h>

#define CIN  32
#define OCH  64
#define HH   56
#define WW   56
#define BB   4
#define OT   4                  // output channels per block
#define IMG  (HH * WW)          // 3136
#define NW   18432              // 64*32*3*3
#define PH   58
#define PW   58
#define PIMG (PH * PW)          // 3364 padded image
#define NXPK (BB * (CIN/2) * PIMG)   // 215296 packed x uints
#define XPKBLKS (NXPK / 256)         // 841 (exact)
#define NWPK (OCH * (CIN/2) * 9)     // 9216 packed weight uints
#define WPKBLKS (NWPK / 256)         // 36 (exact)
#define WOFFu 64                     // packed weights at wsu+64 (uint units)
#define XOFFu (WOFFu + NWPK)         // 9280: packed x follows (256B aligned)

typedef _Float16 h2 __attribute__((ext_vector_type(2)));

// v_pk_min_f16, both operands VGPR (weights now come from LDS).
static __device__ __forceinline__ h2 pkmin_vv(h2 xv, unsigned wu) {
    unsigned xu = __builtin_bit_cast(unsigned, xv);
    unsigned ru;
    asm("v_pk_min_f16 %0, %1, %2" : "=v"(ru) : "v"(xu), "v"(wu));
    return __builtin_bit_cast(h2, ru);
}

// One dispatch, three jobs (fp16 channel-pair packing):
//   blocks [0,841)    : zero-padded x -> fp16 pairs (ch 2cp, 2cp+1) at wsu+XOFFu
//   blocks [841,877)  : weights -> fp16 pairs at wsu+WOFFu, ordered
//                       [otile][wv][oo][cp_local][t] so each minconv block's
//                       576 dwords are CONTIGUOUS (straight LDS copy)
//   block  877        : mu = mean|w| (fp32) -> ws[0]
__global__ __launch_bounds__(256) void prep(const float* __restrict__ x,
                                            const float* __restrict__ w,
                                            float* __restrict__ ws) {
    unsigned* wsu = reinterpret_cast<unsigned*>(ws);
    if (blockIdx.x < XPKBLKS) {
        int idx = blockIdx.x * 256 + threadIdx.x;      // 0..NXPK-1
        int bc  = idx / PIMG;                          // b*16 + cp
        int r   = idx - bc * PIMG;
        int ph  = r / PW;
        int pw  = r - ph * PW;
        int hh  = ph - 1, wc = pw - 1;
        float v0 = 0.f, v1 = 0.f;
        if ((unsigned)hh < (unsigned)HH && (unsigned)wc < (unsigned)WW) {
            int base = ((bc >> 4) * CIN + (bc & 15) * 2) * IMG + hh * WW + wc;
            v0 = x[base];                              // channel 2cp   (coalesced)
            v1 = x[base + IMG];                        // channel 2cp+1
        }
        h2 p; p.x = (_Float16)v0; p.y = (_Float16)v1;
        wsu[XOFFu + idx] = __builtin_bit_cast(unsigned, p);
        return;
    }
    if (blockIdx.x < XPKBLKS + WPKBLKS) {
        int idx = (blockIdx.x - XPKBLKS) * 256 + threadIdx.x;  // 0..NWPK-1
        // decode [otile][wv][oo][cl][t]
        int otile = idx / 576;
        int r     = idx - otile * 576;
        int wvq   = r / 288;
        int r2    = r - wvq * 288;
        int oo    = r2 / 72;
        int r3    = r2 - oo * 72;
        int cl    = r3 / 9;
        int t     = r3 - cl * 9;
        int o     = otile * OT + oo;
        int cp    = wvq * 8 + cl;
        int src   = o * (CIN * 9) + cp * 18 + t;
        h2 p; p.x = (_Float16)w[src]; p.y = (_Float16)w[src + 9];
        wsu[WOFFu + idx] = __builtin_bit_cast(unsigned, p);
        return;
    }
    // |w| mean (fp32 source) -> ws[0]
    float s = 0.f;
    const float4* w4 = reinterpret_cast<const float4*>(w);
    #pragma unroll
    for (int k = 0; k < 18; ++k) {
        float4 v = w4[k * 256 + threadIdx.x];
        s += fabsf(v.x) + fabsf(v.y) + fabsf(v.z) + fabsf(v.w);
    }
    #pragma unroll
    for (int off = 32; off; off >>= 1) s += __shfl_down(s, off);
    __shared__ float sm[4];
    if ((threadIdx.x & 63) == 0) sm[threadIdx.x >> 6] = s;
    __syncthreads();
    if (threadIdx.x == 0)
        ws[0] = (sm[0] + sm[1] + sm[2] + sm[3]) * (1.0f / (float)NW);
}

// R11 post-mortem: s_load results return OUT-OF-ORDER -> any use forces
// lgkmcnt(0), draining the prefetch batch too. SMEM pipelining is
// structurally impossible. Fix: weights via LDS. DS ops return IN-ORDER, so
// the compiler emits fine-grained lgkmcnt(N) between ds_read_b128 and the
// consuming VALU -> real pipelining. Broadcast address (all lanes same) ->
// no bank conflicts. Staging = one straight 576-dword copy (prep reordered).
// R3 lesson: readfirstlane for anything feeding scalar-expected addressing.
// R2 lesson: all register-array indices compile-time.
__global__ __launch_bounds__(128) void minconv_kernel(const float* __restrict__ ws,
                                                      const float* __restrict__ wts,
                                                      float* __restrict__ out) {
    const unsigned* wsu = reinterpret_cast<const unsigned*>(ws);
    const int lane = threadIdx.x & 63;
    const int wv   = threadIdx.x >> 6;
    const int wvs  = __builtin_amdgcn_readfirstlane(wv);   // SGPR copy
    const int hw = blockIdx.x * 64 + lane;             // 0..3135 exact
    const int o0 = blockIdx.y * OT;
    const int b  = blockIdx.z;
    const int h  = hw / WW;
    const int w  = hw - h * WW;

    const float mu = ws[0];                            // uniform s_load

    __shared__ unsigned wlds[576];                     // this o-tile's weights
    __shared__ float red[2][2][64];                    // epilogue exchange

    // ---- stage weights: straight copy of 576 contiguous dwords ----
    {
        const unsigned* wt = wsu + WOFFu + blockIdx.y * 576;
        const int tid = threadIdx.x;
        *reinterpret_cast<uint4*>(&wlds[tid * 4]) =
            *reinterpret_cast<const uint4*>(&wt[tid * 4]);     // 512 dwords
        if (tid < 64) wlds[512 + tid] = wt[512 + tid];         // remaining 64
    }

    // ---- phase 1: issue ALL 72 x-tap loads (VMEM, pipelined) ----
    const int cp0 = wvs * 8;                           // this wave's channel-pairs
    const unsigned* xq = wsu + XOFFu + (size_t)(b * 16 + cp0) * PIMG + h * PW + w;
    h2 xall[72];                                       // constant-indexed -> VGPRs
    #pragma unroll
    for (int cp = 0; cp < 8; ++cp)
        #pragma unroll
        for (int kh = 0; kh < 3; ++kh)
            #pragma unroll
            for (int kw = 0; kw < 3; ++kw)
                xall[cp * 9 + kh * 3 + kw] =
                    __builtin_bit_cast(h2, xq[cp * PIMG + kh * PW + kw]);

    __syncthreads();                                   // weights staged

    // ---- phase 2: compute; weights via ds_read_b128 (in-order lgkm) ----
    h2 ones; ones.x = (_Float16)1.f; ones.y = (_Float16)1.f;
    float acc0 = 0.f, acc1 = 0.f, acc2 = 0.f, acc3 = 0.f;
    const unsigned* wl = wlds + wv * 288;              // per-wave LDS base

    #pragma unroll
    for (int oo = 0; oo < OT; ++oo) {
        float ae = 0.f, ao = 0.f;                      // even/odd chains
        #pragma unroll
        for (int k = 0; k < 18; ++k) {                 // 18 x ds_read_b128
            uint4 q = *reinterpret_cast<const uint4*>(&wl[oo * 72 + k * 4]);
            h2 m0 = pkmin_vv(xall[k * 4 + 0], q.x);
            ae = __builtin_amdgcn_fdot2(m0, ones, ae, false);
            h2 m1 = pkmin_vv(xall[k * 4 + 1], q.y);
            ao = __builtin_amdgcn_fdot2(m1, ones, ao, false);
            h2 m2 = pkmin_vv(xall[k * 4 + 2], q.z);
            ae = __builtin_amdgcn_fdot2(m2, ones, ae, false);
            h2 m3 = pkmin_vv(xall[k * 4 + 3], q.w);
            ao = __builtin_amdgcn_fdot2(m3, ones, ao, false);
        }
        float a = ae + ao;
        switch (oo) {                                  // literal acc names only
            case 0: acc0 = a; break;
            case 1: acc1 = a; break;
            case 2: acc2 = a; break;
            case 3: acc3 = a; break;
        }
    }

    // cross-wave combine: wave0 keeps oo 0,1; wave1 keeps oo 2,3.
    if (wv == 0) {
        red[0][0][lane] = acc2;
        red[0][1][lane] = acc3;
    } else {
        red[1][0][lane] = acc0;
        red[1][1][lane] = acc1;
    }
    __syncthreads();

    float* ob = out + ((size_t)b * OCH + o0) * IMG + hw;
    if (wv == 0) {
        ob[0]       = mu * (acc0 + red[1][0][lane]);
        ob[IMG]     = mu * (acc1 + red[1][1][lane]);
    } else {
        ob[2 * IMG] = mu * (acc2 + red[0][0][lane]);
        ob[3 * IMG] = mu * (acc3 + red[0][1][lane]);
    }
}

extern "C" void kernel_launch(void* const* d_in, const int* in_sizes, int n_in,
                              void* d_out, int out_size, void* d_ws, size_t ws_size,
                              hipStream_t stream) {
    const float* x   = (const float*)d_in[0];   // 4*32*56*56
    const float* w   = (const float*)d_in[1];   // 64*32*3*3
    float*       out = (float*)d_out;           // 4*64*56*56
    float*       ws  = (float*)d_ws;

    prep<<<XPKBLKS + WPKBLKS + 1, 256, 0, stream>>>(x, w, ws);
    dim3 grid(IMG / 64, OCH / OT, BB);          // 49 x 16 x 4 = 3136 blocks
    minconv_kernel<<<grid, 128, 0, stream>>>(ws, w, out);
}